// Round 2
// baseline (38.360 us; speedup 1.0000x reference)
//
#include <hip/hip_runtime.h>

#define N_ATOMS 100000
#define KNBR    16
#define EPSF    1e-12f
#define BLOCK   128

__global__ void sw_init_out(float* out) { out[0] = 0.0f; }

__global__ __launch_bounds__(BLOCK) void sw_kernel(
    const float* __restrict__ coords,
    const float* __restrict__ Ap, const float* __restrict__ Bp,
    const float* __restrict__ pp, const float* __restrict__ qp,
    const float* __restrict__ sigp, const float* __restrict__ gamp,
    const float* __restrict__ cutp, const float* __restrict__ lamp,
    const float* __restrict__ cb0p, const float* __restrict__ cjkp,
    const int* __restrict__ elements, const int* __restrict__ nbr,
    float* __restrict__ out)
{
    __shared__ float4 comp[KNBR][BLOCK];      // compacted 3-body-eligible neighbors
    __shared__ float wave_part[BLOCK / 64];

    const int tid = threadIdx.x;
    const int i   = blockIdx.x * BLOCK + tid;

    float acc = 0.0f;

    if (i < N_ATOMS) {
        const float xi = coords[3 * i + 0];
        const float yi = coords[3 * i + 1];
        const float zi = coords[3 * i + 2];
        const int   ei = elements[i];

        // tiny parameter tables -> registers (uniform addresses -> scalar loads)
        const float c0 = cutp[0], c1 = cutp[1], c2 = cutp[2];
        const float s0 = sigp[0], s1 = sigp[1], s2 = sigp[2];
        const float A0 = Ap[0],  A1 = Ap[1],  A2 = Ap[2];
        const float B0 = Bp[0],  B1 = Bp[1],  B2 = Bp[2];
        const float p0 = pp[0],  p1 = pp[1],  p2 = pp[2];
        const float q0 = qp[0],  q1 = qp[1],  q2 = qp[2];
        const float g1 = gamp[1];
        const float lam_i = lamp[ei];
        const float cb0_i = cb0p[ei];
        const float cjk_i = cjkp[ei];

        int   cnt = 0;
        float e2  = 0.0f;

        for (int j = 0; j < KNBR; ++j) {
            const int   nj = nbr[i * KNBR + j];
            const int   ej = elements[nj];
            const float xj = coords[3 * nj + 0];
            const float yj = coords[3 * nj + 1];
            const float zj = coords[3 * nj + 2];
            const float dx = xj - xi, dy = yj - yi, dz = zj - zi;
            const float r2  = fmaxf(dx * dx + dy * dy + dz * dz, EPSF);
            const float rij = sqrtf(r2);
            const int   ij  = ei + ej;
            const float cut = (ij == 0) ? c0 : ((ij == 1) ? c1 : c2);

            if (rij < cut) {
                const float sg  = (ij == 0) ? s0 : ((ij == 1) ? s1 : s2);
                const float Aij = (ij == 0) ? A0 : ((ij == 1) ? A1 : A2);
                const float Bij = (ij == 0) ? B0 : ((ij == 1) ? B1 : B2);
                const float pij = (ij == 0) ? p0 : ((ij == 1) ? p1 : p2);
                const float qij = (ij == 0) ? q0 : ((ij == 1) ? q1 : q2);
                const float sr  = sg / rij;
                const float E2  = Aij * (Bij * powf(sr, pij) - powf(sr, qij))
                                      * expf(sg / (rij - cut));
                e2 += E2;
                // 3-body eligibility: species mismatch (=> ij==1, cut==c1 already checked)
                if (ej != ei) {
                    comp[cnt][tid] = make_float4(xj, yj, zj, rij);
                    ++cnt;
                }
            }
        }
        acc = 0.5f * e2;

        // 3-body over compacted (rare) neighbors; formula symmetric in (j,k)
        for (int a = 0; a + 1 < cnt; ++a) {
            const float4 pa = comp[a][tid];
            const float  ra = pa.w;
            const float  ea = g1 / (ra - c1);
            for (int b = a + 1; b < cnt; ++b) {
                const float4 pb = comp[b][tid];
                const float ddx = pa.x - pb.x, ddy = pa.y - pb.y, ddz = pa.z - pb.z;
                const float rjk2 = fmaxf(ddx * ddx + ddy * ddy + ddz * ddz, EPSF);
                const float rjk  = sqrtf(rjk2);
                if (rjk < cjk_i) {
                    const float rb   = pb.w;
                    const float cosv = (ra * ra + rb * rb - rjk2)
                                       / (2.0f * ra * rb);
                    const float dcs  = cosv - cb0_i;
                    const float E3   = lam_i * expf(ea + g1 / (rb - c1)) * dcs * dcs;
                    acc += E3;
                }
            }
        }
    }

    // wave reduce (64 lanes)
    for (int o = 32; o > 0; o >>= 1) acc += __shfl_down(acc, o);
    const int wid  = tid >> 6;
    const int lane = tid & 63;
    if (lane == 0) wave_part[wid] = acc;
    __syncthreads();
    if (tid == 0) {
        float s = 0.0f;
        for (int w = 0; w < BLOCK / 64; ++w) s += wave_part[w];
        atomicAdd(out, s);
    }
}

extern "C" void kernel_launch(void* const* d_in, const int* in_sizes, int n_in,
                              void* d_out, int out_size, void* d_ws, size_t ws_size,
                              hipStream_t stream) {
    const float* coords = (const float*)d_in[0];
    const float* A      = (const float*)d_in[1];
    const float* B      = (const float*)d_in[2];
    const float* p      = (const float*)d_in[3];
    const float* q      = (const float*)d_in[4];
    const float* sigma  = (const float*)d_in[5];
    const float* gamma  = (const float*)d_in[6];
    const float* cutoff = (const float*)d_in[7];
    const float* lam    = (const float*)d_in[8];
    const float* cb0    = (const float*)d_in[9];
    const float* cjk    = (const float*)d_in[10];
    const int*   elems  = (const int*)d_in[11];
    const int*   nbr    = (const int*)d_in[12];
    float* out = (float*)d_out;

    sw_init_out<<<1, 1, 0, stream>>>(out);
    const int grid = (N_ATOMS + BLOCK - 1) / BLOCK;
    sw_kernel<<<grid, BLOCK, 0, stream>>>(coords, A, B, p, q, sigma, gamma,
                                          cutoff, lam, cb0, cjk, elems, nbr, out);
}